// Round 9
// baseline (148.723 us; speedup 1.0000x reference)
//
#include <hip/hip_runtime.h>
#include <math.h>

#define MM 8
#define SS 4
#define NLEAF 20
#define KINT 19
#define NBR 38                   // total branches: 2 + 18*2
#define PFLOATS (NBR*MM*16)      // 4864 floats of P matrices (row-major)
#define NNODE 39
#define BLK 256                  // threads per block (4 waves)
#define SPB 512                  // sites per block (2 per thread, stride-64 pairs)

typedef float v2f __attribute__((ext_vector_type(2)));
typedef float v4f __attribute__((ext_vector_type(4)));

// ---------------- setup: Q build + 304 small expm (fp64), row-major P ----------------

__device__ __forceinline__ void mat4_mul(const double a[4][4], const double b[4][4], double c[4][4]) {
    #pragma unroll
    for (int i = 0; i < 4; i++)
        #pragma unroll
        for (int j = 0; j < 4; j++) {
            double s = 0.0;
            #pragma unroll
            for (int k = 0; k < 4; k++) s += a[i][k] * b[k][j];
            c[i][j] = s;
        }
}

__global__ void setup_kernel(const float* __restrict__ rates,
                             const float* __restrict__ pi_inv,
                             const float* __restrict__ rho,
                             const float* __restrict__ T,
                             float* __restrict__ ws)   // [NBR][MM][4][4] row-major, then pi[MM][4]
{
    int tid = blockIdx.x * blockDim.x + threadIdx.x;
    if (tid >= NBR * MM) return;
    int m = tid & 7;
    int k = tid >> 3;

    // pi = inv_stereographic_projection(pi_inv)^2
    double y0 = pi_inv[m*3+0], y1 = pi_inv[m*3+1], y2 = pi_inv[m*3+2];
    double ns  = y0*y0 + y1*y1 + y2*y2;
    double inv = 1.0 / (ns + 1.0);
    double p[4] = {2.0*y0*inv, 2.0*y1*inv, 2.0*y2*inv, (ns-1.0)*inv};
    #pragma unroll
    for (int i = 0; i < 4; i++) p[i] *= p[i];

    if (k == 0) {
        #pragma unroll
        for (int i = 0; i < 4; i++) ws[PFLOATS + m*4 + i] = (float)p[i];
    }

    // Q from squared rates
    double r[6];
    #pragma unroll
    for (int i = 0; i < 6; i++) { double v = rates[m*6+i]; r[i] = v*v; }
    double Q[4][4] = {};
    Q[0][1]=r[0]; Q[0][2]=r[1]; Q[0][3]=r[2]; Q[1][2]=r[3]; Q[1][3]=r[4]; Q[2][3]=r[5];
    #pragma unroll
    for (int i = 0; i < 4; i++)
        #pragma unroll
        for (int j = i+1; j < 4; j++) Q[j][i] = Q[i][j];
    #pragma unroll
    for (int i = 0; i < 4; i++)
        #pragma unroll
        for (int j = 0; j < 4; j++) Q[i][j] *= p[j];
    double emut = 0.0;
    #pragma unroll
    for (int i = 0; i < 4; i++) {
        double rs = 0.0;
        #pragma unroll
        for (int j = 0; j < 4; j++) if (j != i) rs += Q[i][j];
        Q[i][i] = -rs;
        emut += p[i] * rs;
    }
    emut = fmax(emut, 1e-9);
    double scq = (double)rho[m] / emut;

    // branch length for branch k (caterpillar)
    double t;
    if      (k == 0) t = T[0*NNODE + NLEAF];
    else if (k == 1) t = T[1*NNODE + NLEAF];
    else {
        int j     = k >> 1;                       // 1..18
        int node  = NLEAF + j;
        int child = (k & 1) ? (j + 1) : (NLEAF - 1 + j);
        t = T[child*NNODE + node];
    }

    double A[4][4];
    #pragma unroll
    for (int i = 0; i < 4; i++)
        #pragma unroll
        for (int j = 0; j < 4; j++) A[i][j] = Q[i][j] * scq * t;

    // expm: scale to norm <= 2^-4, Taylor(9), square back
    double nrm = 0.0;
    #pragma unroll
    for (int i = 0; i < 4; i++) {
        double rs = 0.0;
        #pragma unroll
        for (int j = 0; j < 4; j++) rs += fabs(A[i][j]);
        nrm = fmax(nrm, rs);
    }
    int s = 0;
    if (nrm > 0.0625) s = (int)ceil(log2(nrm * 16.0));
    if (s < 0) s = 0;
    if (s > 60) s = 60;
    double scl = ldexp(1.0, -s);
    double B[4][4];
    #pragma unroll
    for (int i = 0; i < 4; i++)
        #pragma unroll
        for (int j = 0; j < 4; j++) B[i][j] = A[i][j] * scl;

    double E[4][4];
    #pragma unroll
    for (int i = 0; i < 4; i++)
        #pragma unroll
        for (int j = 0; j < 4; j++) E[i][j] = (i == j) ? 1.0 : 0.0;
    for (int kk = 9; kk >= 1; --kk) {
        double Tm[4][4];
        mat4_mul(B, E, Tm);
        double ik = 1.0 / (double)kk;
        #pragma unroll
        for (int i = 0; i < 4; i++)
            #pragma unroll
            for (int j = 0; j < 4; j++) E[i][j] = ((i == j) ? 1.0 : 0.0) + Tm[i][j] * ik;
    }
    for (int q = 0; q < s; q++) {
        double Tm[4][4];
        mat4_mul(E, E, Tm);
        #pragma unroll
        for (int i = 0; i < 4; i++)
            #pragma unroll
            for (int j = 0; j < 4; j++) E[i][j] = Tm[i][j];
    }

    // ROW-MAJOR store: Pout[c*4+d] = E[c][d]  (consumed as uniform scalars)
    float* Pout = ws + (k*MM + m) * 16;
    #pragma unroll
    for (int c = 0; c < 4; c++)
        #pragma unroll
        for (int d = 0; d < 4; d++) Pout[c*4+d] = (float)E[c][d];
}

// ---------------- main: 2 sites packed in pk-lanes; P consumed from SGPRs ----------------

// t[c] = sum_d P[c*4+d] * S[d]   (P uniform -> SGPR scalar operand of v_pk_fma)
__device__ __forceinline__ void matvp(const float* __restrict__ Pm,
                                      const v2f S0, const v2f S1, const v2f S2, const v2f S3,
                                      v2f t[4])
{
    #pragma unroll
    for (int c = 0; c < 4; c++) {
        float p0 = Pm[c*4+0], p1 = Pm[c*4+1], p2 = Pm[c*4+2], p3 = Pm[c*4+3];
        v2f acc = (v2f){p0, p0} * S0;
        acc = __builtin_elementwise_fma((v2f){p1, p1}, S1, acc);
        acc = __builtin_elementwise_fma((v2f){p2, p2}, S2, acc);
        acc = __builtin_elementwise_fma((v2f){p3, p3}, S3, acc);
        t[c] = acc;
    }
}

__global__ __launch_bounds__(BLK) void phylo_kernel(const float* __restrict__ X,
                                                    const float* __restrict__ ws,
                                                    float* __restrict__ out,
                                                    int batch)
{
    const int lane = threadIdx.x & 63;
    const int w    = threadIdx.x >> 6;
    const int s0   = blockIdx.x * SPB + w * 128 + lane;   // site pair: s0, s0+64
    const int s1   = s0 + 64;
    const int c0   = s0 < batch ? s0 : batch - 1;
    const int c1   = s1 < batch ? s1 : batch - 1;
    const v4f* __restrict__ xs0 = (const v4f*)X + (size_t)c0 * 20;
    const v4f* __restrict__ xs1 = (const v4f*)X + (size_t)c1 * 20;
    const float* __restrict__ P = ws;                     // uniform -> s_load

    v2f S[MM][4];    // state: {site0, site1} per (m, c)   = 64 VGPR

    // ---- step 0: node 20 = (leaf0, leaf1) ----
    {
        v4f a0 = xs0[0], b0 = xs1[0];
        v4f a1 = xs0[1], b1 = xs1[1];
        v2f x0[4], x1[4];
        #pragma unroll
        for (int d = 0; d < 4; d++) { x0[d] = (v2f){a0[d], b0[d]}; x1[d] = (v2f){a1[d], b1[d]}; }
        #pragma unroll
        for (int m = 0; m < MM; m++) {
            const float* __restrict__ P0 = P + (0*MM + m)*16;
            const float* __restrict__ P1 = P + (1*MM + m)*16;
            v2f t[4], u[4];
            matvp(P0, x0[0], x0[1], x0[2], x0[3], t);
            matvp(P1, x1[0], x1[1], x1[2], x1[3], u);
            #pragma unroll
            for (int c = 0; c < 4; c++) S[m][c] = t[c] * u[c];
        }
    }

    // ---- steps 1..18: node 20+j = (internal 19+j, leaf j+1); double-buffered X ----
    v4f na = xs0[2], nb = xs1[2];
    #pragma unroll 1
    for (int j = 1; j < KINT; j++) {
        v2f xl[4];
        #pragma unroll
        for (int d = 0; d < 4; d++) xl[d] = (v2f){na[d], nb[d]};
        if (j < KINT - 1) { na = xs0[j + 2]; nb = xs1[j + 2]; }   // prefetch next leaf

        const float* __restrict__ PI = P + (2*j*MM)*16;   // internal-child block (uniform)
        const float* __restrict__ PL = PI + MM*16;        // leaf-child block
        #pragma unroll
        for (int m = 0; m < MM; m++) {
            v2f t[4], u[4];
            matvp(PI + m*16, S[m][0], S[m][1], S[m][2], S[m][3], t);
            matvp(PL + m*16, xl[0], xl[1], xl[2], xl[3], u);
            #pragma unroll
            for (int c = 0; c < 4; c++) S[m][c] = t[c] * u[c];
        }
    }

    // ---- epilogue: out[site, m] = sum_c S[m][c] * pi[m][c] ----
    v2f r[MM];
    #pragma unroll
    for (int m = 0; m < MM; m++) {
        const float* __restrict__ pim = P + PFLOATS + m*4;
        float q0 = pim[0], q1 = pim[1], q2 = pim[2], q3 = pim[3];
        v2f acc = (v2f){q0, q0} * S[m][0];
        acc = __builtin_elementwise_fma((v2f){q1, q1}, S[m][1], acc);
        acc = __builtin_elementwise_fma((v2f){q2, q2}, S[m][2], acc);
        acc = __builtin_elementwise_fma((v2f){q3, q3}, S[m][3], acc);
        r[m] = acc;
    }
    if (s0 < batch) {
        v4f* __restrict__ o4 = (v4f*)(out + (size_t)s0 * MM);
        o4[0] = (v4f){r[0].x, r[1].x, r[2].x, r[3].x};
        o4[1] = (v4f){r[4].x, r[5].x, r[6].x, r[7].x};
    }
    if (s1 < batch) {
        v4f* __restrict__ o4 = (v4f*)(out + (size_t)s1 * MM);
        o4[0] = (v4f){r[0].y, r[1].y, r[2].y, r[3].y};
        o4[1] = (v4f){r[4].y, r[5].y, r[6].y, r[7].y};
    }
}

// ---------------- launch ----------------

extern "C" void kernel_launch(void* const* d_in, const int* in_sizes, int n_in,
                              void* d_out, int out_size, void* d_ws, size_t ws_size,
                              hipStream_t stream)
{
    const float* X      = (const float*)d_in[0];
    const float* rates  = (const float*)d_in[1];
    const float* pi_inv = (const float*)d_in[2];
    const float* rho    = (const float*)d_in[3];
    const float* T      = (const float*)d_in[4];
    float* out = (float*)d_out;
    float* ws  = (float*)d_ws;

    int batch = in_sizes[0] / (NLEAF * SS);

    hipLaunchKernelGGL(setup_kernel, dim3(1), dim3(320), 0, stream,
                       rates, pi_inv, rho, T, ws);

    int grid = (batch + SPB - 1) / SPB;
    hipLaunchKernelGGL(phylo_kernel, dim3(grid), dim3(BLK), 0, stream,
                       X, ws, out, batch);
}

// Round 11
// 135.571 us; speedup vs baseline: 1.0970x; 1.0970x over previous
//
#include <hip/hip_runtime.h>
#include <math.h>

#define MM 8
#define SS 4
#define NLEAF 20
#define KINT 19
#define NBR 38                   // total branches: 2 + 18*2
#define PFLOATS (NBR*MM*16)      // 4864 floats of P matrices (column-major per matrix)
#define NNODE 39
#define BLK 256                  // 4 waves: (site-group x m-half)
#define SPB 128                  // sites per block

typedef float v2f __attribute__((ext_vector_type(2)));
typedef float v4f __attribute__((ext_vector_type(4)));

// ---------------- setup: Q build + 304 small expm (fp64), stores P COLUMN-MAJOR ----------------

__device__ __forceinline__ void mat4_mul(const double a[4][4], const double b[4][4], double c[4][4]) {
    #pragma unroll
    for (int i = 0; i < 4; i++)
        #pragma unroll
        for (int j = 0; j < 4; j++) {
            double s = 0.0;
            #pragma unroll
            for (int k = 0; k < 4; k++) s += a[i][k] * b[k][j];
            c[i][j] = s;
        }
}

__global__ void setup_kernel(const float* __restrict__ rates,
                             const float* __restrict__ pi_inv,
                             const float* __restrict__ rho,
                             const float* __restrict__ T,
                             float* __restrict__ ws)   // [NBR][MM][16] col-major, then pi[MM][4]
{
    int tid = blockIdx.x * blockDim.x + threadIdx.x;
    if (tid >= NBR * MM) return;
    int m = tid & 7;
    int k = tid >> 3;

    // pi = inv_stereographic_projection(pi_inv)^2
    double y0 = pi_inv[m*3+0], y1 = pi_inv[m*3+1], y2 = pi_inv[m*3+2];
    double ns  = y0*y0 + y1*y1 + y2*y2;
    double inv = 1.0 / (ns + 1.0);
    double p[4] = {2.0*y0*inv, 2.0*y1*inv, 2.0*y2*inv, (ns-1.0)*inv};
    #pragma unroll
    for (int i = 0; i < 4; i++) p[i] *= p[i];

    if (k == 0) {
        #pragma unroll
        for (int i = 0; i < 4; i++) ws[PFLOATS + m*4 + i] = (float)p[i];
    }

    // Q from squared rates
    double r[6];
    #pragma unroll
    for (int i = 0; i < 6; i++) { double v = rates[m*6+i]; r[i] = v*v; }
    double Q[4][4] = {};
    Q[0][1]=r[0]; Q[0][2]=r[1]; Q[0][3]=r[2]; Q[1][2]=r[3]; Q[1][3]=r[4]; Q[2][3]=r[5];
    #pragma unroll
    for (int i = 0; i < 4; i++)
        #pragma unroll
        for (int j = i+1; j < 4; j++) Q[j][i] = Q[i][j];
    #pragma unroll
    for (int i = 0; i < 4; i++)
        #pragma unroll
        for (int j = 0; j < 4; j++) Q[i][j] *= p[j];
    double emut = 0.0;
    #pragma unroll
    for (int i = 0; i < 4; i++) {
        double rs = 0.0;
        #pragma unroll
        for (int j = 0; j < 4; j++) if (j != i) rs += Q[i][j];
        Q[i][i] = -rs;
        emut += p[i] * rs;
    }
    emut = fmax(emut, 1e-9);
    double scq = (double)rho[m] / emut;

    // branch length for branch k (caterpillar)
    double t;
    if      (k == 0) t = T[0*NNODE + NLEAF];
    else if (k == 1) t = T[1*NNODE + NLEAF];
    else {
        int j     = k >> 1;                       // 1..18
        int node  = NLEAF + j;
        int child = (k & 1) ? (j + 1) : (NLEAF - 1 + j);
        t = T[child*NNODE + node];
    }

    double A[4][4];
    #pragma unroll
    for (int i = 0; i < 4; i++)
        #pragma unroll
        for (int j = 0; j < 4; j++) A[i][j] = Q[i][j] * scq * t;

    // expm: scale to norm <= 2^-4, Taylor(9), square back
    double nrm = 0.0;
    #pragma unroll
    for (int i = 0; i < 4; i++) {
        double rs = 0.0;
        #pragma unroll
        for (int j = 0; j < 4; j++) rs += fabs(A[i][j]);
        nrm = fmax(nrm, rs);
    }
    int s = 0;
    if (nrm > 0.0625) s = (int)ceil(log2(nrm * 16.0));
    if (s < 0) s = 0;
    if (s > 60) s = 60;
    double scl = ldexp(1.0, -s);
    double B[4][4];
    #pragma unroll
    for (int i = 0; i < 4; i++)
        #pragma unroll
        for (int j = 0; j < 4; j++) B[i][j] = A[i][j] * scl;

    double E[4][4];
    #pragma unroll
    for (int i = 0; i < 4; i++)
        #pragma unroll
        for (int j = 0; j < 4; j++) E[i][j] = (i == j) ? 1.0 : 0.0;
    for (int kk = 9; kk >= 1; --kk) {
        double Tm[4][4];
        mat4_mul(B, E, Tm);
        double ik = 1.0 / (double)kk;
        #pragma unroll
        for (int i = 0; i < 4; i++)
            #pragma unroll
            for (int j = 0; j < 4; j++) E[i][j] = ((i == j) ? 1.0 : 0.0) + Tm[i][j] * ik;
    }
    for (int q = 0; q < s; q++) {
        double Tm[4][4];
        mat4_mul(E, E, Tm);
        #pragma unroll
        for (int i = 0; i < 4; i++)
            #pragma unroll
            for (int j = 0; j < 4; j++) E[i][j] = Tm[i][j];
    }

    // COLUMN-MAJOR store: Pout[d*4 + c] = E[c][d]  => {P[0][d],P[1][d]} and {P[2][d],P[3][d]}
    // are aligned consecutive pairs (SGPR-pair operands of v_pk_fma_f32)
    float* Pout = ws + (k*MM + m) * 16;
    #pragma unroll
    for (int d = 0; d < 4; d++)
        #pragma unroll
        for (int c = 0; c < 4; c++) Pout[d*4+c] = (float)E[c][d];
}

// ---------------- main: 1 site x 4 mixtures per thread; m-half per wave; P from SGPR pairs ----------------

#define SHUF(v,a,b) __builtin_shufflevector((v),(v),(a),(b))

// t[c] = sum_d P[c][d]*op[d], col-major P (16 floats, uniform -> SGPR pairs).
// op given pair-packed: op_lo={op0,op1}, op_hi={op2,op3}. Out: tlo={t0,t1}, thi={t2,t3}.
__device__ __forceinline__ void matvc(const float* __restrict__ Pm,
                                      v2f op_lo, v2f op_hi, v2f& tlo, v2f& thi)
{
    v2f c0l = (v2f){Pm[0],  Pm[1]},  c0h = (v2f){Pm[2],  Pm[3]};
    v2f c1l = (v2f){Pm[4],  Pm[5]},  c1h = (v2f){Pm[6],  Pm[7]};
    v2f c2l = (v2f){Pm[8],  Pm[9]},  c2h = (v2f){Pm[10], Pm[11]};
    v2f c3l = (v2f){Pm[12], Pm[13]}, c3h = (v2f){Pm[14], Pm[15]};
    v2f a0 = SHUF(op_lo,0,0), a1 = SHUF(op_lo,1,1);
    v2f a2 = SHUF(op_hi,0,0), a3 = SHUF(op_hi,1,1);
    v2f l = c0l * a0, h = c0h * a0;
    l = __builtin_elementwise_fma(c1l, a1, l); h = __builtin_elementwise_fma(c1h, a1, h);
    l = __builtin_elementwise_fma(c2l, a2, l); h = __builtin_elementwise_fma(c2h, a2, h);
    l = __builtin_elementwise_fma(c3l, a3, l); h = __builtin_elementwise_fma(c3h, a3, h);
    tlo = l; thi = h;
}

__global__ __launch_bounds__(BLK) void phylo_kernel(const float* __restrict__ X,
                                                    const float* __restrict__ ws,
                                                    float* __restrict__ out,
                                                    int batch)
{
    const int lane = threadIdx.x & 63;
    const int w    = threadIdx.x >> 6;
    const int mh   = __builtin_amdgcn_readfirstlane(w >> 1);  // mixture half (0/1), forced SGPR
    const int sg   = w & 1;                                   // site group within block
    const int sraw = blockIdx.x * SPB + sg * 64 + lane;
    const int site = sraw < batch ? sraw : batch - 1;
    const v4f* __restrict__ xs = (const v4f*)X + (size_t)site * 20;
    const float* __restrict__ P = ws;
    const int mbase = mh * 4;                                 // this wave's 4 mixtures

    v2f Slo[4], Shi[4];    // state for 4 mixtures, c-pair packed = 16 VGPR

    // ---- step 0: node 20 = (leaf0, leaf1) ----
    {
        v4f x0 = xs[0], x1 = xs[1];
        v2f x0l = (v2f){x0.x, x0.y}, x0h = (v2f){x0.z, x0.w};
        v2f x1l = (v2f){x1.x, x1.y}, x1h = (v2f){x1.z, x1.w};
        #pragma unroll
        for (int mi = 0; mi < 4; mi++) {
            const float* __restrict__ P0 = P + (0*MM + mbase + mi)*16;
            const float* __restrict__ P1 = P + (1*MM + mbase + mi)*16;
            v2f tl, th, ul, uh;
            matvc(P0, x0l, x0h, tl, th);
            matvc(P1, x1l, x1h, ul, uh);
            Slo[mi] = tl*ul; Shi[mi] = th*uh;
        }
    }

    // ---- steps 1..18: node 20+j = (internal 19+j, leaf j+1); double-buffered X ----
    v4f xa = xs[2];
    #pragma unroll 1
    for (int j = 1; j < KINT; j++) {
        v4f xn = xa;
        if (j < KINT - 1) xn = xs[j + 2];                     // prefetch next leaf
        v2f xl = (v2f){xa.x, xa.y}, xh = (v2f){xa.z, xa.w};
        const float* __restrict__ PI = P + (2*j*MM + mbase)*16;   // internal-child (uniform)
        const float* __restrict__ PL = PI + MM*16;                // leaf-child
        #pragma unroll
        for (int mi = 0; mi < 4; mi++) {
            v2f tl, th, ul, uh;
            matvc(PI + mi*16, Slo[mi], Shi[mi], tl, th);
            matvc(PL + mi*16, xl, xh, ul, uh);
            Slo[mi] = tl*ul; Shi[mi] = th*uh;
        }
        xa = xn;
    }

    // ---- epilogue: out[site, mbase+mi] = sum_c S[c] * pi[c] ----
    const float* __restrict__ pip = P + PFLOATS + mbase*4;
    float r[4];
    #pragma unroll
    for (int mi = 0; mi < 4; mi++) {
        v2f plo = (v2f){pip[mi*4+0], pip[mi*4+1]};
        v2f phi = (v2f){pip[mi*4+2], pip[mi*4+3]};
        v2f s = __builtin_elementwise_fma(Shi[mi], phi, Slo[mi] * plo);
        r[mi] = s.x + s.y;
    }
    if (sraw < batch) {
        v4f* __restrict__ o4 = (v4f*)(out + (size_t)sraw * MM + mbase);
        o4[0] = (v4f){r[0], r[1], r[2], r[3]};
    }
}

// ---------------- launch ----------------

extern "C" void kernel_launch(void* const* d_in, const int* in_sizes, int n_in,
                              void* d_out, int out_size, void* d_ws, size_t ws_size,
                              hipStream_t stream)
{
    const float* X      = (const float*)d_in[0];
    const float* rates  = (const float*)d_in[1];
    const float* pi_inv = (const float*)d_in[2];
    const float* rho    = (const float*)d_in[3];
    const float* T      = (const float*)d_in[4];
    float* out = (float*)d_out;
    float* ws  = (float*)d_ws;

    int batch = in_sizes[0] / (NLEAF * SS);

    hipLaunchKernelGGL(setup_kernel, dim3(1), dim3(320), 0, stream,
                       rates, pi_inv, rho, T, ws);

    int grid = (batch + SPB - 1) / SPB;
    hipLaunchKernelGGL(phylo_kernel, dim3(grid), dim3(BLK), 0, stream,
                       X, ws, out, batch);
}